// Round 20
// baseline (64820.844 us; speedup 1.0000x reference)
//
#include <hip/hip_runtime.h>
#include <cstdint>

// DROP_MODE 3 = JAX partitionable threefry, bits = x0^x1  (VERIFIED r3+: absmax 0.0039)

static constexpr int TDEC = 400, TENC = 300, NMEL = 80;
static constexpr int RING = 16;

__device__ __forceinline__ uint2 threefry2x32(uint32_t k0, uint32_t k1,
                                              uint32_t x0, uint32_t x1) {
  uint32_t k2 = k0 ^ k1 ^ 0x1BD11BDAu;
  x0 += k0; x1 += k1;
#define TFR(r) { x0 += x1; x1 = (x1 << (r)) | (x1 >> (32 - (r))); x1 ^= x0; }
  TFR(13) TFR(15) TFR(26) TFR(6)
  x0 += k1; x1 += k2 + 1u;
  TFR(17) TFR(29) TFR(16) TFR(24)
  x0 += k2; x1 += k0 + 2u;
  TFR(13) TFR(15) TFR(26) TFR(6)
  x0 += k0; x1 += k1 + 3u;
  TFR(17) TFR(29) TFR(16) TFR(24)
  x0 += k1; x1 += k2 + 4u;
  TFR(13) TFR(15) TFR(26) TFR(6)
  x0 += k2; x1 += k0 + 5u;
#undef TFR
  return make_uint2(x0, x1);
}

__device__ __forceinline__ bool keep_mask(uint32_t key0, uint32_t key1, uint32_t idx) {
  uint2 o = threefry2x32(key0, key1, 0u, idx);
  uint32_t bits = o.x ^ o.y;
  float u = __uint_as_float((bits >> 9) | 0x3f800000u) - 1.0f;
  return u < 0.5f;
}

__device__ __forceinline__ float dot4(float4 w, float4 a) {
  return w.x * a.x + w.y * a.y + w.z * a.z + w.w * a.w;
}
__device__ __forceinline__ float nt_load(const float* p) {
  return __builtin_nontemporal_load(p);
}
__device__ __forceinline__ void nt_store(float* p, float v) {
  __builtin_nontemporal_store(v, p);
}

// ---- bypass (LLC coherence point) helpers ------------------------------------
__device__ __forceinline__ void s_rel(float* p, float v) {
  __hip_atomic_store(p, v, __ATOMIC_RELAXED, __HIP_MEMORY_SCOPE_AGENT);
}
__device__ __forceinline__ void si_rel(int* p, int v) {
  __hip_atomic_store(p, v, __ATOMIC_RELAXED, __HIP_MEMORY_SCOPE_AGENT);
}
__device__ __forceinline__ float l_rel(const float* p) {
  return __hip_atomic_load(p, __ATOMIC_RELAXED, __HIP_MEMORY_SCOPE_AGENT);
}
__device__ __forceinline__ int li_rel(const int* p) {
  return __hip_atomic_load(p, __ATOMIC_RELAXED, __HIP_MEMORY_SCOPE_AGENT);
}

__device__ __forceinline__ void wait_ge(const int* p, int tgt) {
  while (li_rel(p) < tgt) __builtin_amdgcn_s_sleep(1);
}

// ---- 4-block row-local sync (master q==0), monotone val ------------------------
__device__ __forceinline__ void rsync4(int* arr, int* rel, int r, int q, int val) {
  __syncthreads();
  if (q == 0) {
    if (threadIdx.x < 3) wait_ge(&arr[(r * 4 + 1 + threadIdx.x) * 32], val);
    __syncthreads();
    if (threadIdx.x == 0) si_rel(&rel[r * 32], val);
  } else {
    if (threadIdx.x == 0) {
      si_rel(&arr[(r * 4 + q) * 32], val);
      wait_ge(&rel[r * 32], val);
    }
  }
  __syncthreads();
}

// ---- prenet (teacher-forced, all 400 steps parallel; verified) ---------------
template <int K>
__device__ __forceinline__ void prenet_layer(const float* in_lds, float* out_lds,
                                             float* out_g, const float* __restrict__ W,
                                             uint32_t key0, uint32_t key1, int b0) {
  const int tid = threadIdx.x;
  const int cgp = tid & 63, bg = tid >> 6;
  float acc[4][4];
#pragma unroll
  for (int cc = 0; cc < 4; ++cc)
#pragma unroll
    for (int rr = 0; rr < 4; ++rr) acc[cc][rr] = 0.f;
  const float4* W4 = (const float4*)W;
  const float4* in4 = (const float4*)in_lds;
  for (int k4 = 0; k4 < K / 4; ++k4) {
    float4 a[4];
#pragma unroll
    for (int rr = 0; rr < 4; ++rr) a[rr] = in4[(bg * 4 + rr) * (K / 4) + k4];
#pragma unroll
    for (int cc = 0; cc < 4; ++cc) {
      float4 w = W4[(cgp + 64 * cc) * (K / 4) + k4];
#pragma unroll
      for (int rr = 0; rr < 4; ++rr) acc[cc][rr] += dot4(w, a[rr]);
    }
  }
#pragma unroll
  for (int cc = 0; cc < 4; ++cc)
#pragma unroll
    for (int rr = 0; rr < 4; ++rr) {
      int c = cgp + 64 * cc, br = bg * 4 + rr;
      float val = fmaxf(acc[cc][rr], 0.f);
      val = keep_mask(key0, key1, (uint32_t)((b0 + br) * 256 + c)) ? val * 2.f : 0.f;
      if (out_lds) out_lds[br * 256 + c] = val;
      if (out_g) out_g[(b0 + br) * 256 + c] = val;
    }
  __syncthreads();
}

__global__ __launch_bounds__(256) void prenet_kernel(const float* __restrict__ mels,
                                                     const float* __restrict__ Wp0,
                                                     const float* __restrict__ Wp1,
                                                     const float* __restrict__ Wp2,
                                                     float* __restrict__ x_all) {
  __shared__ float bufA[16 * 256];
  __shared__ float bufB[16 * 256];
  const int t = blockIdx.x >> 1, b0 = (blockIdx.x & 1) * 16;
  const int tid = threadIdx.x;
  for (int i = tid; i < 16 * 80; i += 256) {
    int br = i / 80, k = i % 80;
    bufB[br * 80 + k] = (t == 0) ? 0.f : mels[((b0 + br) * TDEC + (t - 1)) * NMEL + k];
  }
  __syncthreads();
  uint2 k0v = threefry2x32(0u, 42u, 0u, (uint32_t)(t * 3 + 0));
  uint2 k1v = threefry2x32(0u, 42u, 0u, (uint32_t)(t * 3 + 1));
  uint2 k2v = threefry2x32(0u, 42u, 0u, (uint32_t)(t * 3 + 2));
  prenet_layer<80>(bufB, bufA, nullptr, Wp0, k0v.x, k0v.y, b0);
  prenet_layer<256>(bufA, bufB, nullptr, Wp1, k1v.x, k1v.y, b0);
  prenet_layer<256>(bufB, nullptr, x_all + t * 8192, Wp2, k2v.x, k2v.y, b0);
}

// ---- pmem = enc @ Wm.T (verified) ---------------------------------------------
__global__ __launch_bounds__(256) void pmem_kernel(const float* __restrict__ enc,
                                                   const float* __restrict__ Wm,
                                                   float* __restrict__ pmem) {
  const int b = blockIdx.x / 10, pc = blockIdx.x % 10;
  const int j = threadIdx.x & 127, ph = threadIdx.x >> 7;
  const float4* Wm4 = (const float4*)Wm;
  const float4* enc4 = (const float4*)enc + (size_t)(b * 300 + pc * 30 + ph * 15) * 128;
  float acc[15];
#pragma unroll
  for (int pp = 0; pp < 15; ++pp) acc[pp] = 0.f;
  for (int k4 = 0; k4 < 128; ++k4) {
    float4 w = Wm4[j * 128 + k4];
#pragma unroll
    for (int pp = 0; pp < 15; ++pp) acc[pp] += dot4(w, enc4[pp * 128 + k4]);
  }
#pragma unroll
  for (int pp = 0; pp < 15; ++pp)
    pmem[(size_t)(b * 300 + pc * 30 + ph * 15 + pp) * 128 + j] = acc[pp];
}

// ---- persistent decoder: ROW-DECOUPLED, zero chip-wide syncs -------------------
struct DP {
  const float *xall, *enc, *pmem;
  const int* lens;
  const float *Wiha, *Whha, *biha, *bhha;
  const float *Wihd, *Whhd, *bihd, *bhhd;
  const float *Wq, *Kloc, *Wl, *vv, *Wout, *bout, *Wg, *bg;
  float *ah, *ctxM;        // ring-16 x [32][512], bypass
  float *dh;               // [2][32][512]
  float *e2;               // [2][32][304]
  float *pM, *pS;          // [2][32][4]
  float *V;                // [2][128][512]
  float *awsum2;           // [2][32][300]
  int *arrA, *relA, *arrD, *relD, *rM, *attRow, *decRow;
  float *omel, *ogate, *oalign;
};

__global__ __launch_bounds__(256, 1) void decoder_kernel(DP P) {
  __shared__ float scr[6144];     // 24.6KB : GRU partial reduce / E overlay ONLY
  __shared__ float stg[1536];     //  6.1KB : state staging (never aliased by scr)
  __shared__ float2 tapsL[992];   //  7.9KB
  __shared__ float pmemL[9600];   // 38.4KB (att only)
  const int tid = threadIdx.x, blk = blockIdx.x;
  const bool isAtt = (blk < 128);
  const int lb = isAtt ? blk : (blk - 128);
  const int r = lb >> 2, q = lb & 3;
  const int pb = q * 75;          // att position quarter
  const int hg = tid >> 3, seg = tid & 7;

  if (isAtt) {
    for (int i = tid; i < 992; i += 256) {
      int f = i / 31, k = i % 31;
      tapsL[i] = make_float2(P.Kloc[f * 62 + k], P.Kloc[f * 62 + 31 + k]);
    }
    for (int i = tid; i < 9600; i += 256) {
      int pl = i >> 7, c = i & 127;
      pmemL[pl * 128 + c] = P.pmem[((size_t)(r * 300 + pb + pl)) * 128 + c];
    }
  }
  __syncthreads();

  if (isAtt) {
    // ======================= ATT (r, h/pos-quarter q) =======================
    float* xS = stg;          // 256
    float* cS = stg + 256;    // 512
    float* hS = stg + 768;    // 512
    for (int t = 0; t <= TDEC; ++t) {
      const int p0 = t & 1, p1 = p0 ^ 1;
      const int sc = t & (RING - 1), sp = (t - 1) & (RING - 1);
      float* ahC = P.ah + sc * 16384;
      const float* ahP = P.ah + sp * 16384;
      const float* ctxP = P.ctxM + sp * 16384;

      if ((t & 7) == 0) {  // ring back-pressure, row-local
        if (tid == 0) wait_ge(&P.decRow[r * 32], t - 8);
        __syncthreads();
      }

      // ---- G: attGRU row r, h-dims [q*128, q*128+128) ----
      if (t < TDEC) {
        {
          float xv = P.xall[(size_t)t * 8192 + r * 256 + tid];
          float c0 = l_rel(&ctxP[r * 512 + tid]);
          float c1 = l_rel(&ctxP[r * 512 + 256 + tid]);
          float h0 = l_rel(&ahP[r * 512 + tid]);
          float h1 = l_rel(&ahP[r * 512 + 256 + tid]);
          xS[tid] = xv;
          cS[tid] = c0; cS[256 + tid] = c1;
          hS[tid] = h0; hS[256 + tid] = h1;
        }
        __syncthreads();
        const float4* xS4 = (const float4*)xS;
        const float4* cS4 = (const float4*)cS;
        const float4* hS4 = (const float4*)hS;
        const float4* Wih4 = (const float4*)P.Wiha;
        const float4* Whh4 = (const float4*)P.Whha;
        float acc[24];
#pragma unroll
        for (int g = 0; g < 24; ++g) acc[g] = 0.f;
        for (int s = 0; s < 24; ++s) {
          int k4 = s * 8 + seg;
          float4 a = (k4 < 64) ? xS4[k4] : cS4[k4 - 64];
#pragma unroll
          for (int g = 0; g < 3; ++g)
#pragma unroll
            for (int i = 0; i < 4; ++i)
              acc[g * 4 + i] +=
                  dot4(Wih4[(size_t)(g * 512 + q * 128 + hg * 4 + i) * 192 + k4], a);
        }
        for (int s = 0; s < 16; ++s) {
          int k4 = s * 8 + seg;
          float4 h = hS4[k4];
#pragma unroll
          for (int g = 0; g < 3; ++g)
#pragma unroll
            for (int i = 0; i < 4; ++i)
              acc[12 + g * 4 + i] +=
                  dot4(Whh4[(size_t)(g * 512 + q * 128 + hg * 4 + i) * 128 + k4], h);
        }
        __syncthreads();  // all stg reads done before scr reuse is irrelevant; scr-only below
#pragma unroll
        for (int g = 0; g < 24; ++g) scr[(g * 32 + hg) * 8 + seg] = acc[g];
        __syncthreads();
        if (tid < 128) {
          int hglob = q * 128 + tid;
          float gi[3], gh[3];
#pragma unroll
          for (int g = 0; g < 3; ++g) {
            float si = 0.f, sh = 0.f;
#pragma unroll
            for (int s = 0; s < 8; ++s) {
              si += scr[((g * 4 + (tid & 3)) * 32 + (tid >> 2)) * 8 + s];
              sh += scr[((12 + g * 4 + (tid & 3)) * 32 + (tid >> 2)) * 8 + s];
            }
            gi[g] = si + P.biha[g * 512 + hglob];
            gh[g] = sh + P.bhha[g * 512 + hglob];
          }
          float rr = 1.f / (1.f + expf(-(gi[0] + gh[0])));
          float zz = 1.f / (1.f + expf(-(gi[1] + gh[1])));
          float nn = tanhf(gi[2] + rr * gh[2]);
          float hp = hS[q * 128 + tid];   // stg: NOT clobbered by scr partials
          s_rel(&ahC[r * 512 + q * 128 + tid], (1.f - zz) * nn + zz * hp);
        }
      }
      rsync4(P.arrA, P.relA, r, q, 2 * t + 1);

      // ---- E phase (r18-identical math; scr overlay only) ----
      {
        float* awW = scr;            // 105
        float* asW = scr + 105;      // 105
        float* convl = scr + 216;    // 32*77
        float* qp = scr + 2688;      // 256
        float* qb = scr + 2944;      // 128
        float* el = scr + 3072;      // 80
        float* eex = scr + 3152;     // 80
        float* ahS = scr + 3232;     // 512

        if (t < TDEC) {
          float v0s = l_rel(&ahC[r * 512 + tid]);
          float v1s = l_rel(&ahC[r * 512 + 256 + tid]);
          ahS[tid] = v0s;
          ahS[256 + tid] = v1s;
        }
        if (t >= 1) {
          float pMv[4], pSv[4];
#pragma unroll
          for (int j = 0; j < 4; ++j) pMv[j] = l_rel(&P.pM[p1 * 128 + r * 4 + j]);
#pragma unroll
          for (int j = 0; j < 4; ++j) pSv[j] = l_rel(&P.pS[p1 * 128 + r * 4 + j]);
          float M = fmaxf(fmaxf(pMv[0], pMv[1]), fmaxf(pMv[2], pMv[3]));
          float Z = 0.f;
#pragma unroll
          for (int j = 0; j < 4; ++j) Z += pSv[j] * expf(pMv[j] - M);
          float inv = 1.f / Z;
          for (int i = tid; i < 105; i += 256) {
            int p = pb - 15 + i;
            float a = 0.f, s = 0.f;
            if (p >= 0 && p < TENC) {
              float ev = l_rel(&P.e2[p1 * 9728 + r * 304 + p]);
              float sv = l_rel(&P.awsum2[p1 * 9600 + r * 300 + p]);
              a = expf(ev - M) * inv;
              s = sv + a;
            }
            awW[i] = a;
            asW[i] = s;
            if (p >= pb && p < pb + 75) {
              s_rel(&P.awsum2[p0 * 9600 + r * 300 + p], s);
              nt_store(&P.oalign[((size_t)(r * 400 + (t - 1))) * 300 + p], a);
            }
          }
        } else {
          for (int i = tid; i < 105; i += 256) { awW[i] = 0.f; asW[i] = 0.f; }
        }
        __syncthreads();

        if (t < TDEC) {
          {  // conv
            int f = tid & 31, pl0 = tid >> 5;
            for (int pl = pl0; pl < 75; pl += 8) {
              float a = 0.f;
#pragma unroll
              for (int k = 0; k < 31; ++k) {
                float2 tv = tapsL[f * 31 + k];
                a += awW[pl + k] * tv.x + asW[pl + k] * tv.y;
              }
              convl[f * 77 + pl] = a;
            }
          }
          {  // q-proj
            int j = tid & 127, kh = tid >> 7;
            const float4* Wq4 = (const float4*)P.Wq;
            const float4* a4 = (const float4*)ahS;
            float acc = 0.f;
            for (int k4 = kh * 64; k4 < kh * 64 + 64; ++k4)
              acc += dot4(Wq4[j * 128 + k4], a4[k4]);
            qp[j * 2 + kh] = acc;
          }
          __syncthreads();
          if (tid < 128) qb[tid] = qp[tid * 2] + qp[tid * 2 + 1];
          __syncthreads();
          {  // energies (pmem from LDS)
            int w = tid >> 6, lane = tid & 63;
            float wl0[32], wl1[32];
#pragma unroll
            for (int f = 0; f < 32; ++f) {
              wl0[f] = P.Wl[lane * 32 + f];
              wl1[f] = P.Wl[(lane + 64) * 32 + f];
            }
            float v0 = P.vv[lane], v1 = P.vv[lane + 64];
            float q0 = qb[lane], q1 = qb[64 + lane];
            int len = P.lens[r];
            for (int pl = w; pl < 75; pl += 4) {
              int p = pb + pl;
              float a0 = 0.f, a1 = 0.f;
#pragma unroll
              for (int f = 0; f < 32; ++f) {
                float c = convl[f * 77 + pl];
                a0 += c * wl0[f];
                a1 += c * wl1[f];
              }
              float e0 = tanhf(q0 + pmemL[pl * 128 + lane] + a0) * v0;
              float e1 = tanhf(q1 + pmemL[pl * 128 + 64 + lane] + a1) * v1;
              float es = e0 + e1;
#pragma unroll
              for (int off = 32; off > 0; off >>= 1) es += __shfl_xor(es, off, 64);
              if (lane == 0) {
                float ev = (p < len) ? es : -1e9f;
                s_rel(&P.e2[p0 * 9728 + r * 304 + p], ev);
                el[pl] = ev;
              }
            }
          }
          __syncthreads();
          if (tid < 64) {  // slice partials
            int lane = tid;
            float m = -3.4e38f;
            for (int i = lane; i < 75; i += 64) m = fmaxf(m, el[i]);
#pragma unroll
            for (int off = 32; off > 0; off >>= 1) m = fmaxf(m, __shfl_xor(m, off, 64));
            float s = 0.f;
            for (int i = lane; i < 75; i += 64) {
              float x = expf(el[i] - m);
              eex[i] = x;
              s += x;
            }
#pragma unroll
            for (int off = 32; off > 0; off >>= 1) s += __shfl_xor(s, off, 64);
            if (lane == 0) {
              s_rel(&P.pM[p0 * 128 + r * 4 + q], m);
              s_rel(&P.pS[p0 * 128 + r * 4 + q], s);
            }
          }
          __syncthreads();
          {  // V partial (enc NT)
            float* Vw = P.V + (size_t)p0 * 65536 + (size_t)(r * 4 + q) * 512;
#pragma unroll
            for (int cc = 0; cc < 2; ++cc) {
              int c = tid + cc * 256;
              float acc = 0.f;
              const float* eb = P.enc + ((size_t)(r * 300 + pb)) * 512 + c;
              for (int po = 0; po < 75; ++po) acc += eex[po] * nt_load(eb + (size_t)po * 512);
              s_rel(&Vw[c], acc);
            }
          }
          __syncthreads();
          if (tid == 0) si_rel(&P.rM[(r * 4 + q) * 32], t + 1);
          if (q == 0) {  // ctx materialization (row-local sibling sync)
            if (tid < 3) wait_ge(&P.rM[(r * 4 + 1 + tid) * 32], t + 1);
            __syncthreads();
            float pMv[4], pSv[4];
#pragma unroll
            for (int j = 0; j < 4; ++j) pMv[j] = l_rel(&P.pM[p0 * 128 + r * 4 + j]);
#pragma unroll
            for (int j = 0; j < 4; ++j) pSv[j] = l_rel(&P.pS[p0 * 128 + r * 4 + j]);
            float M = fmaxf(fmaxf(pMv[0], pMv[1]), fmaxf(pMv[2], pMv[3]));
            float Z = 0.f, wq[4];
#pragma unroll
            for (int j = 0; j < 4; ++j) {
              wq[j] = expf(pMv[j] - M);
              Z += pSv[j] * wq[j];
            }
            float invZ = 1.f / Z;
            const float* Vb = P.V + (size_t)p0 * 65536 + (size_t)(r * 4) * 512;
            float* ctxC = P.ctxM + sc * 16384;
#pragma unroll
            for (int cc = 0; cc < 2; ++cc) {
              int c = tid + cc * 256;
              float vv4[4];
#pragma unroll
              for (int j = 0; j < 4; ++j) vv4[j] = l_rel(&Vb[j * 512 + c]);
              float acc = vv4[0] * wq[0] + vv4[1] * wq[1] + vv4[2] * wq[2] + vv4[3] * wq[3];
              s_rel(&ctxC[r * 512 + c], acc * invZ);
            }
          }
        }
      }
      rsync4(P.arrA, P.relA, r, q, 2 * t + 2);
      if (q == 0 && tid == 0) si_rel(&P.attRow[r * 32], t + 1);
    }
  } else {
    // ======================= DEC (r, h-quarter q) =======================
    float* aS = stg;           // 512
    float* cS = stg + 512;     // 512
    float* hS = stg + 1024;    // 512
    const int m0 = (q == 0) ? 0 : 21 + 20 * (q - 1);
    const int mcnt = (q == 0) ? 21 : 20;
    for (int t = 0; t < TDEC; ++t) {
      const int p0 = t & 1, p1 = p0 ^ 1;
      const int sc = t & (RING - 1);
      const float* ahC = P.ah + sc * 16384;
      const float* ctxC = P.ctxM + sc * 16384;
      float* dhW = P.dh + p0 * 16384;
      const float* dhP = P.dh + p1 * 16384;

      if (tid == 0) wait_ge(&P.attRow[r * 32], t + 1);
      __syncthreads();

      // ---- decGRU row r, h-dims [q*128, q*128+128) ----
      {
        float a0 = l_rel(&ahC[r * 512 + tid]);
        float a1 = l_rel(&ahC[r * 512 + 256 + tid]);
        float c0 = l_rel(&ctxC[r * 512 + tid]);
        float c1 = l_rel(&ctxC[r * 512 + 256 + tid]);
        float h0 = l_rel(&dhP[r * 512 + tid]);
        float h1 = l_rel(&dhP[r * 512 + 256 + tid]);
        aS[tid] = a0; aS[256 + tid] = a1;
        cS[tid] = c0; cS[256 + tid] = c1;
        hS[tid] = h0; hS[256 + tid] = h1;
      }
      __syncthreads();
      {
        const float4* aS4 = (const float4*)aS;
        const float4* cS4 = (const float4*)cS;
        const float4* hS4 = (const float4*)hS;
        const float4* Wih4 = (const float4*)P.Wihd;
        const float4* Whh4 = (const float4*)P.Whhd;
        float acc[24];
#pragma unroll
        for (int g = 0; g < 24; ++g) acc[g] = 0.f;
        for (int s = 0; s < 32; ++s) {
          int k4 = s * 8 + seg;
          float4 a = (k4 < 128) ? aS4[k4] : cS4[k4 - 128];
#pragma unroll
          for (int g = 0; g < 3; ++g)
#pragma unroll
            for (int i = 0; i < 4; ++i)
              acc[g * 4 + i] +=
                  dot4(Wih4[(size_t)(g * 512 + q * 128 + hg * 4 + i) * 256 + k4], a);
        }
        for (int s = 0; s < 16; ++s) {
          int k4 = s * 8 + seg;
          float4 h = hS4[k4];
#pragma unroll
          for (int g = 0; g < 3; ++g)
#pragma unroll
            for (int i = 0; i < 4; ++i)
              acc[12 + g * 4 + i] +=
                  dot4(Whh4[(size_t)(g * 512 + q * 128 + hg * 4 + i) * 128 + k4], h);
        }
        __syncthreads();
#pragma unroll
        for (int g = 0; g < 24; ++g) scr[(g * 32 + hg) * 8 + seg] = acc[g];
        __syncthreads();
        if (tid < 128) {
          int hglob = q * 128 + tid;
          float gi[3], gh[3];
#pragma unroll
          for (int g = 0; g < 3; ++g) {
            float si = 0.f, sh = 0.f;
#pragma unroll
            for (int s = 0; s < 8; ++s) {
              si += scr[((g * 4 + (tid & 3)) * 32 + (tid >> 2)) * 8 + s];
              sh += scr[((12 + g * 4 + (tid & 3)) * 32 + (tid >> 2)) * 8 + s];
            }
            gi[g] = si + P.bihd[g * 512 + hglob];
            gh[g] = sh + P.bhhd[g * 512 + hglob];
          }
          float rr = 1.f / (1.f + expf(-(gi[0] + gh[0])));
          float zz = 1.f / (1.f + expf(-(gi[1] + gh[1])));
          float nn = tanhf(gi[2] + rr * gh[2]);
          float hp = hS[q * 128 + tid];   // stg: safe
          s_rel(&dhW[r * 512 + q * 128 + tid], (1.f - zz) * nn + zz * hp);
        }
      }
      rsync4(P.arrD, P.relD, r, q, t + 1);
      if (q == 0 && tid == 0) si_rel(&P.decRow[r * 32], t + 1);

      // ---- outproj row r, m-quarter [m0, m0+mcnt) ----
      {
        float* dhS = scr;         // 512 (fresh stage of full dh_t[r])
        float* opl = scr + 512;   // 42
        {
          float d0 = l_rel(&dhW[r * 512 + tid]);
          float d1 = l_rel(&dhW[r * 512 + 256 + tid]);
          dhS[tid] = d0;
          dhS[256 + tid] = d1;
        }
        __syncthreads();
        if (tid < 2 * mcnt) {
          int m = m0 + (tid >> 1), h = tid & 1;
          const float4* W4 = (m < 80) ? ((const float4*)P.Wout + (size_t)m * 256)
                                      : (const float4*)P.Wg;
          const float4* d4 = (const float4*)dhS;
          const float4* c4 = (const float4*)cS;   // stg: still valid
          float a = 0.f;
          for (int k4 = h * 128; k4 < h * 128 + 128; ++k4) {
            float4 x = (k4 < 128) ? d4[k4] : c4[k4 - 128];
            a += dot4(W4[k4], x);
          }
          opl[tid] = a;
        }
        __syncthreads();
        if (tid < mcnt) {
          int m = m0 + tid;
          float sum = opl[tid * 2] + opl[tid * 2 + 1];
          if (m < 80) nt_store(&P.omel[(size_t)(r * 80 + m) * 400 + t], sum + P.bout[m]);
          else nt_store(&P.ogate[r * 400 + t], sum + P.bg[0]);
        }
        __syncthreads();
      }
    }
  }
}

// ---- host -----------------------------------------------------------------------
extern "C" void kernel_launch(void* const* d_in, const int* in_sizes, int n_in,
                              void* d_out, int out_size, void* d_ws, size_t ws_size,
                              hipStream_t stream) {
  const float* enc = (const float*)d_in[0];
  const float* mels = (const float*)d_in[1];
  const int* lens = (const int*)d_in[2];

  float* ws = (float*)d_ws;
  float* x_all = ws;                     // 3,276,800
  float* pmem = x_all + 3276800;         // 1,228,800
  float* ah = pmem + 1228800;            // ring16: 262,144
  float* ctxM = ah + 262144;             // 262,144
  float* dh = ctxM + 262144;             // 32,768
  float* e2 = dh + 32768;                // 19,456
  float* pM = e2 + 19456;                // 256
  float* pS = pM + 256;                  // 256
  float* V = pS + 256;                   // 131,072
  float* awsum2 = V + 131072;            // 19,200
  int* arrA = (int*)(awsum2 + 19200);    // 4,096
  int* relA = arrA + 4096;               // 1,024
  int* arrD = relA + 1024;               // 4,096
  int* relD = arrD + 4096;               // 1,024
  int* rM = relD + 1024;                 // 4,096
  int* attRow = rM + 4096;               // 1,024
  int* decRow = attRow + 1024;           // 1,024

  (void)hipMemsetAsync(ah, 0, (262144 + 262144 + 32768) * sizeof(float), stream);
  (void)hipMemsetAsync(awsum2, 0, 19200 * sizeof(float), stream);
  (void)hipMemsetAsync(arrA, 0,
                       (4096 + 1024 + 4096 + 1024 + 4096 + 1024 + 1024) * sizeof(int),
                       stream);

  prenet_kernel<<<800, 256, 0, stream>>>(mels, (const float*)d_in[3],
                                         (const float*)d_in[4], (const float*)d_in[5],
                                         x_all);
  pmem_kernel<<<320, 256, 0, stream>>>(enc, (const float*)d_in[15], pmem);

  float* omel = (float*)d_out;                  // [32][80][400]
  float* ogate = omel + 32 * 80 * 400;          // [32][400]
  float* oalign = ogate + 32 * 400;             // [32][400][300]

  DP P;
  P.xall = x_all; P.enc = enc; P.pmem = pmem; P.lens = lens;
  P.Wiha = (const float*)d_in[6]; P.Whha = (const float*)d_in[7];
  P.biha = (const float*)d_in[8]; P.bhha = (const float*)d_in[9];
  P.Wihd = (const float*)d_in[10]; P.Whhd = (const float*)d_in[11];
  P.bihd = (const float*)d_in[12]; P.bhhd = (const float*)d_in[13];
  P.Wq = (const float*)d_in[14]; P.Kloc = (const float*)d_in[16];
  P.Wl = (const float*)d_in[17]; P.vv = (const float*)d_in[18];
  P.Wout = (const float*)d_in[19]; P.bout = (const float*)d_in[20];
  P.Wg = (const float*)d_in[21]; P.bg = (const float*)d_in[22];
  P.ah = ah; P.ctxM = ctxM; P.dh = dh; P.e2 = e2; P.pM = pM; P.pS = pS; P.V = V;
  P.awsum2 = awsum2;
  P.arrA = arrA; P.relA = relA; P.arrD = arrD; P.relD = relD; P.rM = rM;
  P.attRow = attRow; P.decRow = decRow;
  P.omel = omel; P.ogate = ogate; P.oalign = oalign;

  decoder_kernel<<<256, 256, 0, stream>>>(P);
}

// Round 21
// 42208.701 us; speedup vs baseline: 1.5357x; 1.5357x over previous
//
#include <hip/hip_runtime.h>
#include <cstdint>

// DROP_MODE 3 = JAX partitionable threefry, bits = x0^x1  (VERIFIED r3+: absmax 0.0039)
// r21 = r18 restored verbatim (best verified: 41.5ms profiled / 42.6ms wall).
// r19/r20's zero-global-barrier row-decoupling regressed (65ms, FETCH 10.9GB):
// LDS weight pinning + 2x128-block relaxed-flag barriers is the best structure found.

static constexpr int TDEC = 400, TENC = 300, NMEL = 80;
static constexpr int RING = 16;

__device__ __forceinline__ uint2 threefry2x32(uint32_t k0, uint32_t k1,
                                              uint32_t x0, uint32_t x1) {
  uint32_t k2 = k0 ^ k1 ^ 0x1BD11BDAu;
  x0 += k0; x1 += k1;
#define TFR(r) { x0 += x1; x1 = (x1 << (r)) | (x1 >> (32 - (r))); x1 ^= x0; }
  TFR(13) TFR(15) TFR(26) TFR(6)
  x0 += k1; x1 += k2 + 1u;
  TFR(17) TFR(29) TFR(16) TFR(24)
  x0 += k2; x1 += k0 + 2u;
  TFR(13) TFR(15) TFR(26) TFR(6)
  x0 += k0; x1 += k1 + 3u;
  TFR(17) TFR(29) TFR(16) TFR(24)
  x0 += k1; x1 += k2 + 4u;
  TFR(13) TFR(15) TFR(26) TFR(6)
  x0 += k2; x1 += k0 + 5u;
#undef TFR
  return make_uint2(x0, x1);
}

__device__ __forceinline__ bool keep_mask(uint32_t key0, uint32_t key1, uint32_t idx) {
  uint2 o = threefry2x32(key0, key1, 0u, idx);
  uint32_t bits = o.x ^ o.y;
  float u = __uint_as_float((bits >> 9) | 0x3f800000u) - 1.0f;
  return u < 0.5f;
}

__device__ __forceinline__ float dot4(float4 w, float4 a) {
  return w.x * a.x + w.y * a.y + w.z * a.z + w.w * a.w;
}
__device__ __forceinline__ float nt_load(const float* p) {
  return __builtin_nontemporal_load(p);
}
__device__ __forceinline__ void nt_store(float* p, float v) {
  __builtin_nontemporal_store(v, p);
}

// ---- bypass (LLC coherence point) helpers ------------------------------------
__device__ __forceinline__ void s_rel(float* p, float v) {
  __hip_atomic_store(p, v, __ATOMIC_RELAXED, __HIP_MEMORY_SCOPE_AGENT);
}
__device__ __forceinline__ void si_rel(int* p, int v) {
  __hip_atomic_store(p, v, __ATOMIC_RELAXED, __HIP_MEMORY_SCOPE_AGENT);
}
__device__ __forceinline__ float l_rel(const float* p) {
  return __hip_atomic_load(p, __ATOMIC_RELAXED, __HIP_MEMORY_SCOPE_AGENT);
}
__device__ __forceinline__ int li_rel(const int* p) {
  return __hip_atomic_load(p, __ATOMIC_RELAXED, __HIP_MEMORY_SCOPE_AGENT);
}
__device__ __forceinline__ float4 l4(const float4* p) {
  const unsigned long long* q = (const unsigned long long*)p;
  unsigned long long a = __hip_atomic_load(q, __ATOMIC_RELAXED, __HIP_MEMORY_SCOPE_AGENT);
  unsigned long long b = __hip_atomic_load(q + 1, __ATOMIC_RELAXED, __HIP_MEMORY_SCOPE_AGENT);
  float4 r;
  ((unsigned long long*)&r)[0] = a;
  ((unsigned long long*)&r)[1] = b;
  return r;
}

__device__ __forceinline__ void wait_ge(const int* p, int tgt) {
  while (li_rel(p) < tgt) __builtin_amdgcn_s_sleep(1);
}

// ---- 128-block flag-tree barrier, relaxed flags (syncthreads drains vmcnt) ----
__device__ __forceinline__ void gsyncN(int* arrive, int* release, int id, int bno) {
  __syncthreads();
  if (id == 0) {
    if (threadIdx.x > 0 && threadIdx.x < 128)
      wait_ge(&arrive[threadIdx.x * 32], bno);
    __syncthreads();
    if (threadIdx.x < 8)
      si_rel(&release[threadIdx.x * 32], bno);
  } else {
    if (threadIdx.x == 0) {
      si_rel(&arrive[id * 32], bno);
      wait_ge(&release[(id & 7) * 32], bno);
    }
  }
  __syncthreads();
}

// ---- prenet (teacher-forced, all 400 steps parallel; verified) ---------------
template <int K>
__device__ __forceinline__ void prenet_layer(const float* in_lds, float* out_lds,
                                             float* out_g, const float* __restrict__ W,
                                             uint32_t key0, uint32_t key1, int b0) {
  const int tid = threadIdx.x;
  const int cgp = tid & 63, bg = tid >> 6;
  float acc[4][4];
#pragma unroll
  for (int cc = 0; cc < 4; ++cc)
#pragma unroll
    for (int rr = 0; rr < 4; ++rr) acc[cc][rr] = 0.f;
  const float4* W4 = (const float4*)W;
  const float4* in4 = (const float4*)in_lds;
  for (int k4 = 0; k4 < K / 4; ++k4) {
    float4 a[4];
#pragma unroll
    for (int rr = 0; rr < 4; ++rr) a[rr] = in4[(bg * 4 + rr) * (K / 4) + k4];
#pragma unroll
    for (int cc = 0; cc < 4; ++cc) {
      float4 w = W4[(cgp + 64 * cc) * (K / 4) + k4];
#pragma unroll
      for (int rr = 0; rr < 4; ++rr) acc[cc][rr] += dot4(w, a[rr]);
    }
  }
#pragma unroll
  for (int cc = 0; cc < 4; ++cc)
#pragma unroll
    for (int rr = 0; rr < 4; ++rr) {
      int c = cgp + 64 * cc, br = bg * 4 + rr;
      float val = fmaxf(acc[cc][rr], 0.f);
      val = keep_mask(key0, key1, (uint32_t)((b0 + br) * 256 + c)) ? val * 2.f : 0.f;
      if (out_lds) out_lds[br * 256 + c] = val;
      if (out_g) out_g[(b0 + br) * 256 + c] = val;
    }
  __syncthreads();
}

__global__ __launch_bounds__(256) void prenet_kernel(const float* __restrict__ mels,
                                                     const float* __restrict__ Wp0,
                                                     const float* __restrict__ Wp1,
                                                     const float* __restrict__ Wp2,
                                                     float* __restrict__ x_all) {
  __shared__ float bufA[16 * 256];
  __shared__ float bufB[16 * 256];
  const int t = blockIdx.x >> 1, b0 = (blockIdx.x & 1) * 16;
  const int tid = threadIdx.x;
  for (int i = tid; i < 16 * 80; i += 256) {
    int br = i / 80, k = i % 80;
    bufB[br * 80 + k] = (t == 0) ? 0.f : mels[((b0 + br) * TDEC + (t - 1)) * NMEL + k];
  }
  __syncthreads();
  uint2 k0v = threefry2x32(0u, 42u, 0u, (uint32_t)(t * 3 + 0));
  uint2 k1v = threefry2x32(0u, 42u, 0u, (uint32_t)(t * 3 + 1));
  uint2 k2v = threefry2x32(0u, 42u, 0u, (uint32_t)(t * 3 + 2));
  prenet_layer<80>(bufB, bufA, nullptr, Wp0, k0v.x, k0v.y, b0);
  prenet_layer<256>(bufA, bufB, nullptr, Wp1, k1v.x, k1v.y, b0);
  prenet_layer<256>(bufB, nullptr, x_all + t * 8192, Wp2, k2v.x, k2v.y, b0);
}

// ---- pmem = enc @ Wm.T (verified) ---------------------------------------------
__global__ __launch_bounds__(256) void pmem_kernel(const float* __restrict__ enc,
                                                   const float* __restrict__ Wm,
                                                   float* __restrict__ pmem) {
  const int b = blockIdx.x / 10, pc = blockIdx.x % 10;
  const int j = threadIdx.x & 127, ph = threadIdx.x >> 7;
  const float4* Wm4 = (const float4*)Wm;
  const float4* enc4 = (const float4*)enc + (size_t)(b * 300 + pc * 30 + ph * 15) * 128;
  float acc[15];
#pragma unroll
  for (int pp = 0; pp < 15; ++pp) acc[pp] = 0.f;
  for (int k4 = 0; k4 < 128; ++k4) {
    float4 w = Wm4[j * 128 + k4];
#pragma unroll
    for (int pp = 0; pp < 15; ++pp) acc[pp] += dot4(w, enc4[pp * 128 + k4]);
  }
#pragma unroll
  for (int pp = 0; pp < 15; ++pp)
    pmem[(size_t)(b * 300 + pc * 30 + ph * 15 + pp) * 128 + j] = acc[pp];
}

// ---- persistent decoder: decoupled att / dec pipelines -------------------------
struct DP {
  const float *xall, *enc, *pmem;
  const int* lens;
  const float *Wiha, *Whha, *biha, *bhha;
  const float *Wihd, *Whhd, *bihd, *bhhd;
  const float *Wq, *Kloc, *Wl, *vv, *Wout, *bout, *Wg, *bg;
  float *ah, *ctxM;        // ring-16 x [32][512], bypass
  float *dh;               // [2][32][512]
  float *e2;               // [2][32][304]
  float *pM, *pS;          // [2][32][4]
  float *V;                // [2][128][512]
  float *awsum2;           // [2][32][300]
  int *arrA, *relA, *arrD, *relD, *rM, *attT, *decT;
  float *omel, *ogate, *oalign;
};

__global__ __launch_bounds__(256, 1) void decoder_kernel(DP P) {
  __shared__ float4 pinW[4608];   // 73.7KB (att uses 3840)
  __shared__ float scr[6144];     // 24.6KB
  __shared__ float2 tapsL[992];   //  7.9KB
  __shared__ float pmemL[9600];   // 38.4KB (att only)
  const int tid = threadIdx.x, blk = blockIdx.x;

  if (blk < 128) {
    // ======================= ATT PIPELINE =======================
    const int er = blk >> 2, eq = blk & 3, pb = eq * 75;
    const int idx0 = blk * 4;
    {  // pin att weights + taps + pmem slice
      const float4* Wih4 = (const float4*)P.Wiha;
      const float4* Whh4 = (const float4*)P.Whha;
      for (int i = tid; i < 2304; i += 256) {
        int g = i / 768, rem = i % 768, r2 = rem / 192, k4 = rem % 192;
        pinW[i] = Wih4[(size_t)(g * 512 + idx0 + r2) * 192 + k4];
      }
      for (int i = tid; i < 1536; i += 256) {
        int g = i / 512, rem = i % 512, r2 = rem / 128, k4 = rem % 128;
        pinW[2304 + i] = Whh4[(size_t)(g * 512 + idx0 + r2) * 128 + k4];
      }
      for (int i = tid; i < 992; i += 256) {
        int f = i / 31, k = i % 31;
        tapsL[i] = make_float2(P.Kloc[f * 62 + k], P.Kloc[f * 62 + 31 + k]);
      }
      for (int i = tid; i < 9600; i += 256) {
        int pl = i >> 7, c = i & 127;
        pmemL[pl * 128 + c] = P.pmem[((size_t)(er * 300 + pb + pl)) * 128 + c];
      }
    }
    __syncthreads();

    int bno = 0;
    for (int t = 0; t <= TDEC; ++t) {
      const int p0 = t & 1, p1 = p0 ^ 1;
      const int sc = t & (RING - 1), sp = (t - 1) & (RING - 1);
      float* ahC = P.ah + sc * 16384;
      const float* ahP = P.ah + sp * 16384;
      const float* ctxP = P.ctxM + sp * 16384;

      // back-pressure every 8 steps (RING=16; induction-safe)
      if ((t & 7) == 0) {
        if (tid == 0) wait_ge(P.decT, t - 4);
        __syncthreads();
      }

      // ---- G_att: ah_t slice [blk*4, blk*4+4) ----
      if (t < TDEC) {
        const int row = tid >> 3, seg = tid & 7;
        const float4* A4p = (const float4*)(P.xall + (size_t)t * 8192);
        const float4* C4 = (const float4*)ctxP;
        const float4* H4 = (const float4*)ahP;
        float acc[24];
#pragma unroll
        for (int g = 0; g < 24; ++g) acc[g] = 0.f;
        for (int sb = 0; sb < 24; sb += 8) {
          float4 av[8];
#pragma unroll
          for (int u = 0; u < 8; ++u) {
            int k4 = (sb + u) * 8 + seg;
            av[u] = (k4 < 64) ? A4p[row * 64 + k4] : l4(&C4[row * 128 + (k4 - 64)]);
          }
#pragma unroll
          for (int u = 0; u < 8; ++u) {
            int k4 = (sb + u) * 8 + seg;
#pragma unroll
            for (int g = 0; g < 3; ++g)
#pragma unroll
              for (int i = 0; i < 4; ++i)
                acc[g * 4 + i] += dot4(pinW[(g * 4 + i) * 192 + k4], av[u]);
          }
        }
        for (int sb = 0; sb < 16; sb += 8) {
          float4 hv[8];
#pragma unroll
          for (int u = 0; u < 8; ++u) {
            int k4 = (sb + u) * 8 + seg;
            hv[u] = l4(&H4[row * 128 + k4]);
          }
#pragma unroll
          for (int u = 0; u < 8; ++u) {
            int k4 = (sb + u) * 8 + seg;
#pragma unroll
            for (int g = 0; g < 3; ++g)
#pragma unroll
              for (int i = 0; i < 4; ++i)
                acc[12 + g * 4 + i] += dot4(pinW[2304 + (g * 4 + i) * 128 + k4], hv[u]);
          }
        }
#pragma unroll
        for (int g = 0; g < 24; ++g) scr[(g * 32 + row) * 8 + seg] = acc[g];
        __syncthreads();
        if (tid < 128) {
          int i = tid >> 5, r = tid & 31;
          float gi[3], gh[3];
#pragma unroll
          for (int g = 0; g < 3; ++g) {
            float si = 0.f, sh = 0.f;
#pragma unroll
            for (int s = 0; s < 8; ++s) {
              si += scr[((g * 4 + i) * 32 + r) * 8 + s];
              sh += scr[((12 + g * 4 + i) * 32 + r) * 8 + s];
            }
            gi[g] = si + P.biha[g * 512 + idx0 + i];
            gh[g] = sh + P.bhha[g * 512 + idx0 + i];
          }
          float rr = 1.f / (1.f + expf(-(gi[0] + gh[0])));
          float zz = 1.f / (1.f + expf(-(gi[1] + gh[1])));
          float nn = tanhf(gi[2] + rr * gh[2]);
          float hp = l_rel(&ahP[r * 512 + idx0 + i]);
          s_rel(&ahC[r * 512 + idx0 + i], (1.f - zz) * nn + zz * hp);
        }
      }
      gsyncN(P.arrA, P.relA, blk, ++bno);

      // ---- E phase ----
      {
        float* awW = scr;            // 105
        float* asW = scr + 105;      // 105
        float* convl = scr + 216;    // 32*77
        float* qp = scr + 2688;      // 256
        float* qb = scr + 2944;      // 128
        float* el = scr + 3072;      // 80
        float* eex = scr + 3152;     // 80
        float* ahS = scr + 3232;     // 512

        if (t < TDEC) {
          float v0s = l_rel(&ahC[er * 512 + tid]);
          float v1s = l_rel(&ahC[er * 512 + 256 + tid]);
          ahS[tid] = v0s;
          ahS[256 + tid] = v1s;
        }
        if (t >= 1) {
          float pMv[4], pSv[4];
#pragma unroll
          for (int j = 0; j < 4; ++j) pMv[j] = l_rel(&P.pM[p1 * 128 + er * 4 + j]);
#pragma unroll
          for (int j = 0; j < 4; ++j) pSv[j] = l_rel(&P.pS[p1 * 128 + er * 4 + j]);
          float M = fmaxf(fmaxf(pMv[0], pMv[1]), fmaxf(pMv[2], pMv[3]));
          float Z = 0.f;
#pragma unroll
          for (int j = 0; j < 4; ++j) Z += pSv[j] * expf(pMv[j] - M);
          float inv = 1.f / Z;
          for (int i = tid; i < 105; i += 256) {
            int p = pb - 15 + i;
            float a = 0.f, s = 0.f;
            if (p >= 0 && p < TENC) {
              float ev = l_rel(&P.e2[p1 * 9728 + er * 304 + p]);
              float sv = l_rel(&P.awsum2[p1 * 9600 + er * 300 + p]);
              a = expf(ev - M) * inv;
              s = sv + a;
            }
            awW[i] = a;
            asW[i] = s;
            if (p >= pb && p < pb + 75) {
              s_rel(&P.awsum2[p0 * 9600 + er * 300 + p], s);
              nt_store(&P.oalign[((size_t)(er * 400 + (t - 1))) * 300 + p], a);
            }
          }
        } else {
          for (int i = tid; i < 105; i += 256) { awW[i] = 0.f; asW[i] = 0.f; }
        }
        __syncthreads();

        if (t < TDEC) {
          {  // conv
            int f = tid & 31, pl0 = tid >> 5;
            for (int pl = pl0; pl < 75; pl += 8) {
              float a = 0.f;
#pragma unroll
              for (int k = 0; k < 31; ++k) {
                float2 tv = tapsL[f * 31 + k];
                a += awW[pl + k] * tv.x + asW[pl + k] * tv.y;
              }
              convl[f * 77 + pl] = a;
            }
          }
          {  // q-proj
            int j = tid & 127, kh = tid >> 7;
            const float4* Wq4 = (const float4*)P.Wq;
            const float4* a4 = (const float4*)ahS;
            float acc = 0.f;
            for (int k4 = kh * 64; k4 < kh * 64 + 64; ++k4)
              acc += dot4(Wq4[j * 128 + k4], a4[k4]);
            qp[j * 2 + kh] = acc;
          }
          __syncthreads();
          if (tid < 128) qb[tid] = qp[tid * 2] + qp[tid * 2 + 1];
          __syncthreads();
          {  // energies (pmem from LDS)
            int w = tid >> 6, lane = tid & 63;
            float wl0[32], wl1[32];
#pragma unroll
            for (int f = 0; f < 32; ++f) {
              wl0[f] = P.Wl[lane * 32 + f];
              wl1[f] = P.Wl[(lane + 64) * 32 + f];
            }
            float v0 = P.vv[lane], v1 = P.vv[lane + 64];
            float q0 = qb[lane], q1 = qb[64 + lane];
            int len = P.lens[er];
            for (int pl = w; pl < 75; pl += 4) {
              int p = pb + pl;
              float a0 = 0.f, a1 = 0.f;
#pragma unroll
              for (int f = 0; f < 32; ++f) {
                float c = convl[f * 77 + pl];
                a0 += c * wl0[f];
                a1 += c * wl1[f];
              }
              float e0 = tanhf(q0 + pmemL[pl * 128 + lane] + a0) * v0;
              float e1 = tanhf(q1 + pmemL[pl * 128 + 64 + lane] + a1) * v1;
              float es = e0 + e1;
#pragma unroll
              for (int off = 32; off > 0; off >>= 1) es += __shfl_xor(es, off, 64);
              if (lane == 0) {
                float ev = (p < len) ? es : -1e9f;
                s_rel(&P.e2[p0 * 9728 + er * 304 + p], ev);
                el[pl] = ev;
              }
            }
          }
          __syncthreads();
          if (tid < 64) {  // slice partials
            int lane = tid;
            float m = -3.4e38f;
            for (int i = lane; i < 75; i += 64) m = fmaxf(m, el[i]);
#pragma unroll
            for (int off = 32; off > 0; off >>= 1) m = fmaxf(m, __shfl_xor(m, off, 64));
            float s = 0.f;
            for (int i = lane; i < 75; i += 64) {
              float x = expf(el[i] - m);
              eex[i] = x;
              s += x;
            }
#pragma unroll
            for (int off = 32; off > 0; off >>= 1) s += __shfl_xor(s, off, 64);
            if (lane == 0) {
              s_rel(&P.pM[p0 * 128 + er * 4 + eq], m);
              s_rel(&P.pS[p0 * 128 + er * 4 + eq], s);
            }
          }
          __syncthreads();
          {  // V partial (enc NT)
            float* Vw = P.V + (size_t)p0 * 65536 + (size_t)(er * 4 + eq) * 512;
#pragma unroll
            for (int cc = 0; cc < 2; ++cc) {
              int c = tid + cc * 256;
              float acc = 0.f;
              const float* eb = P.enc + ((size_t)(er * 300 + pb)) * 512 + c;
              for (int po = 0; po < 75; ++po) acc += eex[po] * nt_load(eb + (size_t)po * 512);
              s_rel(&Vw[c], acc);
            }
          }
          __syncthreads();
          if (tid == 0) si_rel(&P.rM[(er * 4 + eq) * 32], t + 1);
          if (eq == 0) {  // ctx materialization
            if (tid < 3) wait_ge(&P.rM[(er * 4 + 1 + tid) * 32], t + 1);
            __syncthreads();
            float pMv[4], pSv[4];
#pragma unroll
            for (int j = 0; j < 4; ++j) pMv[j] = l_rel(&P.pM[p0 * 128 + er * 4 + j]);
#pragma unroll
            for (int j = 0; j < 4; ++j) pSv[j] = l_rel(&P.pS[p0 * 128 + er * 4 + j]);
            float M = fmaxf(fmaxf(pMv[0], pMv[1]), fmaxf(pMv[2], pMv[3]));
            float Z = 0.f, wq[4];
#pragma unroll
            for (int j = 0; j < 4; ++j) {
              wq[j] = expf(pMv[j] - M);
              Z += pSv[j] * wq[j];
            }
            float invZ = 1.f / Z;
            const float* Vb = P.V + (size_t)p0 * 65536 + (size_t)(er * 4) * 512;
            float* ctxC = P.ctxM + sc * 16384;
#pragma unroll
            for (int cc = 0; cc < 2; ++cc) {
              int c = tid + cc * 256;
              float vv4[4];
#pragma unroll
              for (int j = 0; j < 4; ++j) vv4[j] = l_rel(&Vb[j * 512 + c]);
              float acc = vv4[0] * wq[0] + vv4[1] * wq[1] + vv4[2] * wq[2] + vv4[3] * wq[3];
              s_rel(&ctxC[er * 512 + c], acc * invZ);
            }
          }
        }
      }
      gsyncN(P.arrA, P.relA, blk, ++bno);
      if (blk == 0 && tid == 0) si_rel(P.attT, t + 1);
    }
  } else {
    // ======================= DEC PIPELINE =======================
    const int dblk = blk - 128;
    const int idx0 = dblk * 4;
    const int r_op = dblk >> 2, mq = dblk & 3;
    const int m0 = (mq == 0) ? 0 : 21 + 20 * (mq - 1);
    const int mcnt = (mq == 0) ? 21 : 20;
    {  // pin dec weights
      const float4* Wih4 = (const float4*)P.Wihd;
      const float4* Whh4 = (const float4*)P.Whhd;
      for (int i = tid; i < 3072; i += 256) {
        int g = i / 1024, rem = i % 1024, r2 = rem / 256, k4 = rem % 256;
        pinW[i] = Wih4[(size_t)(g * 512 + idx0 + r2) * 256 + k4];
      }
      for (int i = tid; i < 1536; i += 256) {
        int g = i / 512, rem = i % 512, r2 = rem / 128, k4 = rem % 128;
        pinW[3072 + i] = Whh4[(size_t)(g * 512 + idx0 + r2) * 128 + k4];
      }
    }
    __syncthreads();

    int bno = 0;
    for (int t = 0; t < TDEC; ++t) {
      const int p0 = t & 1, p1 = p0 ^ 1;
      const int sc = t & (RING - 1);
      const float* ahC = P.ah + sc * 16384;
      const float* ctxC = P.ctxM + sc * 16384;
      float* dhW = P.dh + p0 * 16384;
      const float* dhP = P.dh + p1 * 16384;

      if (tid == 0) wait_ge(P.attT, t + 1);
      __syncthreads();

      // ---- decGRU_t: in = [ah_t | ctx_t], h = dh_{t-1} ----
      {
        const int row = tid >> 3, seg = tid & 7;
        const float4* A4 = (const float4*)ahC;
        const float4* C4 = (const float4*)ctxC;
        const float4* H4 = (const float4*)dhP;
        float acc[24];
#pragma unroll
        for (int g = 0; g < 24; ++g) acc[g] = 0.f;
        for (int sb = 0; sb < 32; sb += 8) {
          float4 av[8];
#pragma unroll
          for (int u = 0; u < 8; ++u) {
            int k4 = (sb + u) * 8 + seg;
            av[u] = (k4 < 128) ? l4(&A4[row * 128 + k4]) : l4(&C4[row * 128 + (k4 - 128)]);
          }
#pragma unroll
          for (int u = 0; u < 8; ++u) {
            int k4 = (sb + u) * 8 + seg;
#pragma unroll
            for (int g = 0; g < 3; ++g)
#pragma unroll
              for (int i = 0; i < 4; ++i)
                acc[g * 4 + i] += dot4(pinW[(g * 4 + i) * 256 + k4], av[u]);
          }
        }
        for (int sb = 0; sb < 16; sb += 8) {
          float4 hv[8];
#pragma unroll
          for (int u = 0; u < 8; ++u) {
            int k4 = (sb + u) * 8 + seg;
            hv[u] = l4(&H4[row * 128 + k4]);
          }
#pragma unroll
          for (int u = 0; u < 8; ++u) {
            int k4 = (sb + u) * 8 + seg;
#pragma unroll
            for (int g = 0; g < 3; ++g)
#pragma unroll
              for (int i = 0; i < 4; ++i)
                acc[12 + g * 4 + i] += dot4(pinW[3072 + (g * 4 + i) * 128 + k4], hv[u]);
          }
        }
#pragma unroll
        for (int g = 0; g < 24; ++g) scr[(g * 32 + row) * 8 + seg] = acc[g];
        __syncthreads();
        if (tid < 128) {
          int i = tid >> 5, r = tid & 31;
          float gi[3], gh[3];
#pragma unroll
          for (int g = 0; g < 3; ++g) {
            float si = 0.f, sh = 0.f;
#pragma unroll
            for (int s = 0; s < 8; ++s) {
              si += scr[((g * 4 + i) * 32 + r) * 8 + s];
              sh += scr[((12 + g * 4 + i) * 32 + r) * 8 + s];
            }
            gi[g] = si + P.bihd[g * 512 + idx0 + i];
            gh[g] = sh + P.bhhd[g * 512 + idx0 + i];
          }
          float rr = 1.f / (1.f + expf(-(gi[0] + gh[0])));
          float zz = 1.f / (1.f + expf(-(gi[1] + gh[1])));
          float nn = tanhf(gi[2] + rr * gh[2]);
          float hp = l_rel(&dhP[r * 512 + idx0 + i]);
          s_rel(&dhW[r * 512 + idx0 + i], (1.f - zz) * nn + zz * hp);
        }
      }
      gsyncN(P.arrD, P.relD, dblk, ++bno);
      if (dblk == 0 && tid == 0) si_rel(P.decT, t);

      // ---- outproj_t: row r_op, m in [m0, m0+mcnt) ----
      {
        float* dhcx = scr;        // 1024
        float* opl = scr + 1024;  // 42
        for (int i = tid; i < 512; i += 256) {
          float d0 = l_rel(&dhW[r_op * 512 + i]);
          float c0 = l_rel(&ctxC[r_op * 512 + i]);
          dhcx[i] = d0;
          dhcx[512 + i] = c0;
        }
        __syncthreads();
        if (tid < 2 * mcnt) {
          int m = m0 + (tid >> 1), h = tid & 1;
          const float4* W4 = (m < 80) ? ((const float4*)P.Wout + (size_t)m * 256)
                                      : (const float4*)P.Wg;
          const float4* x4 = (const float4*)dhcx;
          float a = 0.f;
          for (int k4 = h * 128; k4 < h * 128 + 128; ++k4) a += dot4(W4[k4], x4[k4]);
          opl[tid] = a;
        }
        __syncthreads();
        if (tid < mcnt) {
          int m = m0 + tid;
          float sum = opl[tid * 2] + opl[tid * 2 + 1];
          if (m < 80) nt_store(&P.omel[(size_t)(r_op * 80 + m) * 400 + t], sum + P.bout[m]);
          else nt_store(&P.ogate[r_op * 400 + t], sum + P.bg[0]);
        }
        __syncthreads();
      }
    }
  }
}

// ---- host -----------------------------------------------------------------------
extern "C" void kernel_launch(void* const* d_in, const int* in_sizes, int n_in,
                              void* d_out, int out_size, void* d_ws, size_t ws_size,
                              hipStream_t stream) {
  const float* enc = (const float*)d_in[0];
  const float* mels = (const float*)d_in[1];
  const int* lens = (const int*)d_in[2];

  float* ws = (float*)d_ws;
  float* x_all = ws;                     // 3,276,800
  float* pmem = x_all + 3276800;         // 1,228,800
  float* ah = pmem + 1228800;            // ring16: 262,144
  float* ctxM = ah + 262144;             // 262,144
  float* dh = ctxM + 262144;             // 32,768
  float* e2 = dh + 32768;                // 19,456
  float* pM = e2 + 19456;                // 256
  float* pS = pM + 256;                  // 256
  float* V = pS + 256;                   // 131,072
  float* awsum2 = V + 131072;            // 19,200
  int* arrA = (int*)(awsum2 + 19200);    // 4,096
  int* relA = arrA + 4096;               // 256
  int* arrD = relA + 256;                // 4,096
  int* relD = arrD + 4096;               // 256
  int* rM = relD + 256;                  // 4,096
  int* attT = rM + 4096;                 // 32
  int* decT = attT + 32;                 // 32

  (void)hipMemsetAsync(ah, 0, (262144 + 262144 + 32768) * sizeof(float), stream);
  (void)hipMemsetAsync(awsum2, 0, 19200 * sizeof(float), stream);
  (void)hipMemsetAsync(arrA, 0, (4096 + 256 + 4096 + 256 + 4096 + 32 + 32) * sizeof(int),
                       stream);

  prenet_kernel<<<800, 256, 0, stream>>>(mels, (const float*)d_in[3],
                                         (const float*)d_in[4], (const float*)d_in[5],
                                         x_all);
  pmem_kernel<<<320, 256, 0, stream>>>(enc, (const float*)d_in[15], pmem);

  float* omel = (float*)d_out;                  // [32][80][400]
  float* ogate = omel + 32 * 80 * 400;          // [32][400]
  float* oalign = ogate + 32 * 400;             // [32][400][300]

  DP P;
  P.xall = x_all; P.enc = enc; P.pmem = pmem; P.lens = lens;
  P.Wiha = (const float*)d_in[6]; P.Whha = (const float*)d_in[7];
  P.biha = (const float*)d_in[8]; P.bhha = (const float*)d_in[9];
  P.Wihd = (const float*)d_in[10]; P.Whhd = (const float*)d_in[11];
  P.bihd = (const float*)d_in[12]; P.bhhd = (const float*)d_in[13];
  P.Wq = (const float*)d_in[14]; P.Kloc = (const float*)d_in[16];
  P.Wl = (const float*)d_in[17]; P.vv = (const float*)d_in[18];
  P.Wout = (const float*)d_in[19]; P.bout = (const float*)d_in[20];
  P.Wg = (const float*)d_in[21]; P.bg = (const float*)d_in[22];
  P.ah = ah; P.ctxM = ctxM; P.dh = dh; P.e2 = e2; P.pM = pM; P.pS = pS; P.V = V;
  P.awsum2 = awsum2;
  P.arrA = arrA; P.relA = relA; P.arrD = arrD; P.relD = relD; P.rM = rM;
  P.attT = attT; P.decT = decT;
  P.omel = omel; P.ogate = ogate; P.oalign = oalign;

  decoder_kernel<<<256, 256, 0, stream>>>(P);
}